// Round 1
// baseline (894.197 us; speedup 1.0000x reference)
//
#include <hip/hip_runtime.h>

typedef __bf16 bf16x4 __attribute__((ext_vector_type(4)));
typedef __bf16 bf16x8 __attribute__((ext_vector_type(8)));
typedef float  f32x4  __attribute__((ext_vector_type(4)));

#define XS 168   // X row stride (bf16 elems): 336 B; 84 words ≡ 20 (mod 32) -> bank spread
#define HS 136   // H row stride (bf16 elems): 272 B; 68 words ≡ 4  (mod 32) -> bank spread
#define XPLANE (64 * XS * 2)   // 21504 B per X plane
#define HPLANE (64 * HS * 2)   // 17408 B per H plane

__device__ inline f32x4 mfma16(bf16x8 a, bf16x8 b, f32x4 c) {
  return __builtin_amdgcn_mfma_f32_16x16x32_bf16(a, b, c, 0, 0, 0);
}

struct bf2 { __bf16 h, l; };
__device__ inline bf2 split(float x) {
  bf2 r;
  r.h = (__bf16)x;
  r.l = (__bf16)(x - (float)r.h);  // exact residual in fp32
  return r;
}

// x = [ef(32) | nf[src](64) | nf[tgt](64)]  (160 = 5 k-chunks of 32)
// h = relu(x @ W1^T + b1) : 128   (4 k-chunks of 32 for GEMM2)
// o = h @ W2^T + b2 : 64
//
// R3 changes vs R2-best:
//  * LDS union: X planes (43008 B) overlaid with H hi/lo planes (34816 B).
//    43008 B/block -> 3 blocks/CU (was 76800 -> 2). Costs 2 extra barriers/tile.
//  * Swapped MFMA operands in BOTH GEMMs: D = W x X (A=W rows, B=X cols).
//    A/B fragments have identical lane layouts, so the same register frags work;
//    D transposes: lane now holds 4 consecutive j (GEMM1) / 4 consecutive o (GEMM2).
//    -> P2 writes contiguous bf16x4 hi/lo row segments (no u32 packing),
//    -> P3 reads bf16x8 fragments directly (kills 128 v_perm/thread/tile),
//    -> epilogue is 4 float4 stores (was 16 scalar stores).
__global__ __launch_bounds__(256, 3) void edge_mlp(
    const int* __restrict__ eidx, const float* __restrict__ nf,
    const float* __restrict__ ef, const float* __restrict__ W1,
    const float* __restrict__ b1, const float* __restrict__ W2,
    const float* __restrict__ b2, float* __restrict__ out, int E)
{
  __shared__ __attribute__((aligned(16))) char smem[2 * XPLANE];  // 43008 B
  __bf16* const sXh = (__bf16*)smem;
  __bf16* const sXl = (__bf16*)(smem + XPLANE);
  __bf16* const sHh = (__bf16*)smem;            // aliases sXh — barrier-separated
  __bf16* const sHl = (__bf16*)(smem + HPLANE); // aliases sXh tail / sXl head

  const int tid  = threadIdx.x;
  const int lane = tid & 63;
  const int wv   = tid >> 6;     // wave 0..3
  const int l16  = lane & 15;
  const int q    = lane >> 4;    // quad 0..3

  // ---- one-time: W1/W2 hi/lo fragments (used as the A operand now) ----
  bf16x8 w1h[2][5], w1l[2][5];
#pragma unroll
  for (int jt = 0; jt < 2; ++jt) {
    const int j = 32 * wv + 16 * jt + l16;
#pragma unroll
    for (int kc = 0; kc < 5; ++kc) {
      const float* p = W1 + j * 160 + kc * 32 + q * 8;
#pragma unroll
      for (int i = 0; i < 8; ++i) {
        bf2 s = split(p[i]);
        w1h[jt][kc][i] = s.h;
        w1l[jt][kc][i] = s.l;
      }
    }
  }
  bf16x8 w2h[4], w2l[4];
  {
    const int o = 16 * wv + l16;
#pragma unroll
    for (int kc = 0; kc < 4; ++kc) {
      const float* p = W2 + o * 128 + kc * 32 + q * 8;
#pragma unroll
      for (int i = 0; i < 8; ++i) {
        bf2 s = split(p[i]);
        w2h[kc][i] = s.h;
        w2l[kc][i] = s.l;
      }
    }
  }
  // biases: with transposed D, lane's 4 regs are consecutive j / o
  float b1v[2][4], b2v[4];
#pragma unroll
  for (int jt = 0; jt < 2; ++jt)
#pragma unroll
    for (int r = 0; r < 4; ++r) b1v[jt][r] = b1[32 * wv + 16 * jt + 4 * q + r];
#pragma unroll
  for (int r = 0; r < 4; ++r) b2v[r] = b2[16 * wv + 4 * q + r];

  const float4* ef4 = (const float4*)ef;
  const float4* nf4 = (const float4*)nf;

  const int eL = tid >> 2;   // 0..63: edge within tile (gather phase)
  const int qq = tid & 3;    // 4 threads/edge
  const int ntiles = (E + 63) >> 6;

  // ---- prefetch pipeline: gather tile's 10 float4 into g ----
  float4 g[10];
  auto gather = [&](int tile_) {
    int e = tile_ * 64 + eL;
    if (e >= E) e = E - 1;               // tail: duplicate work, stores guarded
    const int s = eidx[e];
    const int t = eidx[E + e];
#pragma unroll
    for (int i = 0; i < 10; ++i) {
      const int fi = qq + 4 * i;         // i<2: ef, i<6: nf[src], else nf[tgt]
      const float4* p = (i < 2) ? (ef4 + e * 8 + fi)
                      : (i < 6) ? (nf4 + s * 16 + (fi - 8))
                                : (nf4 + t * 16 + (fi - 24));
      g[i] = *p;
    }
  };

  int tile = blockIdx.x;
  if (tile < ntiles) gather(tile);

  for (; tile < ntiles; tile += gridDim.x) {
    const int e0 = tile << 6;

    __syncthreads();  // bar A: prev-tile P3 H-reads done before X writes (union)

    // ---- P0': split prefetched regs into X planes ----
#pragma unroll
    for (int i = 0; i < 10; ++i) {
      const int fi = qq + 4 * i;
      const float4 v = g[i];
      bf16x4 hv, lv;
      { bf2 s0 = split(v.x); hv[0] = s0.h; lv[0] = s0.l; }
      { bf2 s1 = split(v.y); hv[1] = s1.h; lv[1] = s1.l; }
      { bf2 s2 = split(v.z); hv[2] = s2.h; lv[2] = s2.l; }
      { bf2 s3 = split(v.w); hv[3] = s3.h; lv[3] = s3.l; }
      *(bf16x4*)&sXh[eL * XS + fi * 4] = hv;
      *(bf16x4*)&sXl[eL * XS + fi * 4] = lv;
    }
    __syncthreads();  // bar B

    // ---- issue next tile's gather NOW; reg loads are waited at use (next P0')
    {
      const int nxt = tile + gridDim.x;
      if (nxt < ntiles) gather(nxt);
    }

    // ---- P1: GEMM1 swapped: D[j][e] = W1(A) x X(B); acc1[jt][et] ----
    f32x4 acc1[2][4];
#pragma unroll
    for (int jt = 0; jt < 2; ++jt)
#pragma unroll
      for (int et = 0; et < 4; ++et) acc1[jt][et] = (f32x4){0.f, 0.f, 0.f, 0.f};

#pragma unroll
    for (int kc = 0; kc < 5; ++kc) {
#pragma unroll
      for (int ep = 0; ep < 4; ep += 2) {
        bf16x8 xh[2], xl[2];
#pragma unroll
        for (int m = 0; m < 2; ++m) {
          const int off = (16 * (ep + m) + l16) * XS + kc * 32 + q * 8;
          xh[m] = *(const bf16x8*)&sXh[off];
          xl[m] = *(const bf16x8*)&sXl[off];
        }
        // same three products as before: {WhXh, WhXl(=XlWh), WlXh(=XhWl)}
#pragma unroll
        for (int m = 0; m < 2; ++m)
#pragma unroll
          for (int jt = 0; jt < 2; ++jt)
            acc1[jt][ep + m] = mfma16(w1h[jt][kc], xh[m], acc1[jt][ep + m]);
#pragma unroll
        for (int m = 0; m < 2; ++m)
#pragma unroll
          for (int jt = 0; jt < 2; ++jt)
            acc1[jt][ep + m] = mfma16(w1h[jt][kc], xl[m], acc1[jt][ep + m]);
#pragma unroll
        for (int m = 0; m < 2; ++m)
#pragma unroll
          for (int jt = 0; jt < 2; ++jt)
            acc1[jt][ep + m] = mfma16(w1l[jt][kc], xh[m], acc1[jt][ep + m]);
      }
    }

    __syncthreads();  // bar C: all X reads done before H writes (union)

    // ---- P2: bias+relu+split; lane's 4 regs = consecutive j -> b64 row writes
    // write bank base = (4*l16 + 16wv+8jt+2q) mod 32: 2 addrs/bank max (free)
#pragma unroll
    for (int jt = 0; jt < 2; ++jt) {
#pragma unroll
      for (int et = 0; et < 4; ++et) {
        bf16x4 hh, hl;
#pragma unroll
        for (int r = 0; r < 4; ++r) {
          const float h = fmaxf(acc1[jt][et][r] + b1v[jt][r], 0.f);
          bf2 s = split(h);
          hh[r] = s.h; hl[r] = s.l;
        }
        const int base = (16 * et + l16) * HS + 32 * wv + 16 * jt + 4 * q;
        *(bf16x4*)&sHh[base] = hh;
        *(bf16x4*)&sHl[base] = hl;
      }
    }
    __syncthreads();  // bar D

    // ---- P3: GEMM2 swapped: D[o][e] = W2(A) x H(B); direct bf16x8 reads ----
    f32x4 acc2[4];
#pragma unroll
    for (int et = 0; et < 4; ++et) acc2[et] = (f32x4){0.f, 0.f, 0.f, 0.f};

#pragma unroll
    for (int kc = 0; kc < 4; ++kc) {
      bf16x8 hh[4], hl[4];
#pragma unroll
      for (int et = 0; et < 4; ++et) {
        const int off = (16 * et + l16) * HS + kc * 32 + q * 8;
        hh[et] = *(const bf16x8*)&sHh[off];
        hl[et] = *(const bf16x8*)&sHl[off];
      }
#pragma unroll
      for (int et = 0; et < 4; ++et) acc2[et] = mfma16(w2h[kc], hh[et], acc2[et]);
#pragma unroll
      for (int et = 0; et < 4; ++et) acc2[et] = mfma16(w2h[kc], hl[et], acc2[et]);
#pragma unroll
      for (int et = 0; et < 4; ++et) acc2[et] = mfma16(w2l[kc], hh[et], acc2[et]);
    }

    // ---- store: lane holds 4 consecutive o at one edge -> float4 stores ----
#pragma unroll
    for (int et = 0; et < 4; ++et) {
      const int e = e0 + 16 * et + l16;
      if (e < E) {
        f32x4 o;
#pragma unroll
        for (int r = 0; r < 4; ++r) o[r] = acc2[et][r] + b2v[r];
        *(f32x4*)&out[e * 64 + 16 * wv + 4 * q] = o;
      }
    }
  }
}

extern "C" void kernel_launch(void* const* d_in, const int* in_sizes, int n_in,
                              void* d_out, int out_size, void* d_ws, size_t ws_size,
                              hipStream_t stream) {
  const int*   eidx = (const int*)d_in[0];
  const float* nf   = (const float*)d_in[1];
  const float* ef   = (const float*)d_in[2];
  const float* W1   = (const float*)d_in[3];
  const float* b1   = (const float*)d_in[4];
  const float* W2   = (const float*)d_in[5];
  const float* b2   = (const float*)d_in[6];
  float* out = (float*)d_out;
  const int E = in_sizes[0] / 2;

  // grid divisible by both 512 (2 blk/CU) and 768 (3 blk/CU) residency,
  // so block-waves stay balanced even if occupancy lands at 2.
  dim3 grid(1536), block(256);
  hipLaunchKernelGGL(edge_mlp, grid, block, 0, stream,
                     eidx, nf, ef, W1, b1, W2, b2, out, E);
}

// Round 2
// 811.808 us; speedup vs baseline: 1.1015x; 1.1015x over previous
//
#include <hip/hip_runtime.h>

typedef __bf16 bf16x4 __attribute__((ext_vector_type(4)));
typedef __bf16 bf16x8 __attribute__((ext_vector_type(8)));
typedef float  f32x4  __attribute__((ext_vector_type(4)));

#define XS 168   // X row stride (bf16 elems): 336 B rows, 16B-aligned for b128
#define HS 136   // H row stride (bf16 elems): 272 B rows, 16B-aligned for b128
#define XPLANE (64 * XS * 2)   // 21504 B per X plane
#define HPLANE (64 * HS * 2)   // 17408 B per H plane

__device__ inline f32x4 mfma16(bf16x8 a, bf16x8 b, f32x4 c) {
  return __builtin_amdgcn_mfma_f32_16x16x32_bf16(a, b, c, 0, 0, 0);
}

struct bf2 { __bf16 h, l; };
__device__ inline bf2 split(float x) {
  bf2 r;
  r.h = (__bf16)x;
  r.l = (__bf16)(x - (float)r.h);  // exact residual in fp32
  return r;
}

// x = [ef(32) | nf[src](64) | nf[tgt](64)]  (160 = 5 k-chunks of 32)
// h = relu(x @ W1^T + b1) : 128   (4 k-chunks of 32 for GEMM2)
// o = h @ W2^T + b2 : 64
//
// R2 (post R1 spill disaster): 8-wave (512-thread) blocks, per-wave state
// halved so the live set (~115 VGPR) fits the 128-VGPR cap of
// __launch_bounds__(512,4) -> 2 blocks/CU x 8 waves = 16 waves/CU, NO spills.
//   wave w: GEMM1 j-slice [16w,16w+16)   (W1 frags resident: 40 VGPR)
//           GEMM2 o-slice 16*(w&3), edges [32*(w>>2), +32)  (W2 streamed)
// R1 lesson: launch_bounds(256,3) forced spills (VGPR 84 << ~190 live) ->
// ~1GB scratch traffic (FETCH 438->1347 MB). Fit by construction, not force.
__global__ __launch_bounds__(512, 4) void edge_mlp(
    const int* __restrict__ eidx, const float* __restrict__ nf,
    const float* __restrict__ ef, const float* __restrict__ W1,
    const float* __restrict__ b1, const float* __restrict__ W2,
    const float* __restrict__ b2, float* __restrict__ out, int E)
{
  __shared__ __attribute__((aligned(16))) char smem[2 * XPLANE];  // 43008 B
  __bf16* const sXh = (__bf16*)smem;
  __bf16* const sXl = (__bf16*)(smem + XPLANE);
  __bf16* const sHh = (__bf16*)smem;            // aliases sXh — barrier-separated
  __bf16* const sHl = (__bf16*)(smem + HPLANE);

  const int tid  = threadIdx.x;
  const int lane = tid & 63;
  const int w    = tid >> 6;     // wave 0..7
  const int l16  = lane & 15;
  const int q    = lane >> 4;    // quad 0..3

  // ---- one-time: resident W1 fragments for this wave's 16-j slice (40 VGPR)
  bf16x8 w1h[5], w1l[5];
#pragma unroll
  for (int kc = 0; kc < 5; ++kc) {
    const float4* p = (const float4*)(W1 + (16 * w + l16) * 160 + kc * 32 + q * 8);
    const float4 a = p[0], b = p[1];
    bf2 s;
    s = split(a.x); w1h[kc][0] = s.h; w1l[kc][0] = s.l;
    s = split(a.y); w1h[kc][1] = s.h; w1l[kc][1] = s.l;
    s = split(a.z); w1h[kc][2] = s.h; w1l[kc][2] = s.l;
    s = split(a.w); w1h[kc][3] = s.h; w1l[kc][3] = s.l;
    s = split(b.x); w1h[kc][4] = s.h; w1l[kc][4] = s.l;
    s = split(b.y); w1h[kc][5] = s.h; w1l[kc][5] = s.l;
    s = split(b.z); w1h[kc][6] = s.h; w1l[kc][6] = s.l;
    s = split(b.w); w1h[kc][7] = s.h; w1l[kc][7] = s.l;
  }
  float b1v[4], b2v[4];
#pragma unroll
  for (int r = 0; r < 4; ++r) b1v[r] = b1[16 * w + 4 * q + r];
  const int os    = w & 3;          // GEMM2 o-slice
  const int ebase = 32 * (w >> 2);  // GEMM2 edge-half base
#pragma unroll
  for (int r = 0; r < 4; ++r) b2v[r] = b2[16 * os + 4 * q + r];

  const float4* ef4 = (const float4*)ef;
  const float4* nf4 = (const float4*)nf;

  const int eL = tid >> 3;   // 0..63: edge within tile (gather phase)
  const int qq = tid & 7;    // 8 threads/edge
  const int ntiles = (E + 63) >> 6;

  // ---- prefetch pipeline: gather tile's 5 float4 into g (20 VGPR) ----
  float4 g[5];
  auto gather = [&](int tile_) {
    int e = tile_ * 64 + eL;
    if (e >= E) e = E - 1;               // tail: duplicate work, stores guarded
    const int s = eidx[e];
    const int t = eidx[E + e];
#pragma unroll
    for (int i = 0; i < 5; ++i) {
      const int fi = qq + 8 * i;         // i=0: ef, i=1,2: nf[src], i=3,4: nf[tgt]
      const float4* p = (i < 1) ? (ef4 + e * 8 + qq)
                      : (i < 3) ? (nf4 + s * 16 + (fi - 8))
                                : (nf4 + t * 16 + (fi - 24));
      g[i] = *p;
    }
  };

  int tile = blockIdx.x;
  if (tile < ntiles) gather(tile);

  for (; tile < ntiles; tile += gridDim.x) {
    const int e0 = tile << 6;

    __syncthreads();  // bar A: prev-tile P3 H-reads done before X writes (union)

    // ---- P0': split prefetched regs into X planes ----
#pragma unroll
    for (int i = 0; i < 5; ++i) {
      const int fi = qq + 8 * i;
      const float4 v = g[i];
      bf16x4 hv, lv;
      { bf2 s0 = split(v.x); hv[0] = s0.h; lv[0] = s0.l; }
      { bf2 s1 = split(v.y); hv[1] = s1.h; lv[1] = s1.l; }
      { bf2 s2 = split(v.z); hv[2] = s2.h; lv[2] = s2.l; }
      { bf2 s3 = split(v.w); hv[3] = s3.h; lv[3] = s3.l; }
      *(bf16x4*)&sXh[eL * XS + fi * 4] = hv;
      *(bf16x4*)&sXl[eL * XS + fi * 4] = lv;
    }
    __syncthreads();  // bar B

    // ---- issue next tile's gather NOW; overlaps P1, drained at bar C ----
    {
      const int nxt = tile + gridDim.x;
      if (nxt < ntiles) gather(nxt);
    }

    // ---- P1: GEMM1  D[j][e] = W1(A) x X(B); wave's 16-j slice, all 64 e ----
    f32x4 acc1[4];
#pragma unroll
    for (int et = 0; et < 4; ++et) acc1[et] = (f32x4){0.f, 0.f, 0.f, 0.f};

#pragma unroll
    for (int kc = 0; kc < 5; ++kc) {
#pragma unroll
      for (int ep = 0; ep < 4; ep += 2) {
        bf16x8 xh[2], xl[2];
#pragma unroll
        for (int m = 0; m < 2; ++m) {
          const int off = (16 * (ep + m) + l16) * XS + kc * 32 + q * 8;
          xh[m] = *(const bf16x8*)&sXh[off];
          xl[m] = *(const bf16x8*)&sXl[off];
        }
        // three products: {WhXh, WhXl, WlXh}
#pragma unroll
        for (int m = 0; m < 2; ++m)
          acc1[ep + m] = mfma16(w1h[kc], xh[m], acc1[ep + m]);
#pragma unroll
        for (int m = 0; m < 2; ++m)
          acc1[ep + m] = mfma16(w1h[kc], xl[m], acc1[ep + m]);
#pragma unroll
        for (int m = 0; m < 2; ++m)
          acc1[ep + m] = mfma16(w1l[kc], xh[m], acc1[ep + m]);
      }
    }

    __syncthreads();  // bar C: all X reads done before H writes (union)

    // ---- P2: bias+relu+split; lane's 4 regs = consecutive j -> b64 writes ----
#pragma unroll
    for (int et = 0; et < 4; ++et) {
      bf16x4 hh, hl;
#pragma unroll
      for (int r = 0; r < 4; ++r) {
        const float h = fmaxf(acc1[et][r] + b1v[r], 0.f);
        bf2 s = split(h);
        hh[r] = s.h; hl[r] = s.l;
      }
      const int base = (16 * et + l16) * HS + 16 * w + 4 * q;
      *(bf16x4*)&sHh[base] = hh;
      *(bf16x4*)&sHl[base] = hl;
    }
    __syncthreads();  // bar D

    // ---- P3: GEMM2  D[o][e] = W2(A) x H(B); W2 streamed per kc (L2-hot).
    // Gather was drained at bar C, so W2's vmcnt waits stall nothing else.
    f32x4 acc2[2];
    acc2[0] = (f32x4){0.f, 0.f, 0.f, 0.f};
    acc2[1] = (f32x4){0.f, 0.f, 0.f, 0.f};

#pragma unroll
    for (int kc = 0; kc < 4; ++kc) {
      const float4* wp = (const float4*)(W2 + (16 * os + l16) * 128 + kc * 32 + q * 8);
      asm volatile("" : "+v"(wp));   // anti-hoist: keep the load inside the tile loop
      const float4 wa = wp[0], wb = wp[1];
      bf16x8 w2h, w2l;
      {
        bf2 s;
        s = split(wa.x); w2h[0] = s.h; w2l[0] = s.l;
        s = split(wa.y); w2h[1] = s.h; w2l[1] = s.l;
        s = split(wa.z); w2h[2] = s.h; w2l[2] = s.l;
        s = split(wa.w); w2h[3] = s.h; w2l[3] = s.l;
        s = split(wb.x); w2h[4] = s.h; w2l[4] = s.l;
        s = split(wb.y); w2h[5] = s.h; w2l[5] = s.l;
        s = split(wb.z); w2h[6] = s.h; w2l[6] = s.l;
        s = split(wb.w); w2h[7] = s.h; w2l[7] = s.l;
      }
#pragma unroll
      for (int eh = 0; eh < 2; ++eh) {
        const int off = (ebase + 16 * eh + l16) * HS + kc * 32 + q * 8;
        const bf16x8 hh = *(const bf16x8*)&sHh[off];
        const bf16x8 hl = *(const bf16x8*)&sHl[off];
        acc2[eh] = mfma16(w2h, hh, acc2[eh]);
        acc2[eh] = mfma16(w2h, hl, acc2[eh]);
        acc2[eh] = mfma16(w2l, hh, acc2[eh]);
      }
    }

    // ---- store: lane holds 4 consecutive o at one edge -> float4 stores ----
#pragma unroll
    for (int eh = 0; eh < 2; ++eh) {
      const int e = e0 + ebase + 16 * eh + l16;
      if (e < E) {
        f32x4 o;
#pragma unroll
        for (int r = 0; r < 4; ++r) o[r] = acc2[eh][r] + b2v[r];
        *(f32x4*)&out[e * 64 + 16 * os + 4 * q] = o;
      }
    }
  }
}

extern "C" void kernel_launch(void* const* d_in, const int* in_sizes, int n_in,
                              void* d_out, int out_size, void* d_ws, size_t ws_size,
                              hipStream_t stream) {
  const int*   eidx = (const int*)d_in[0];
  const float* nf   = (const float*)d_in[1];
  const float* ef   = (const float*)d_in[2];
  const float* W1   = (const float*)d_in[3];
  const float* b1   = (const float*)d_in[4];
  const float* W2   = (const float*)d_in[5];
  const float* b2   = (const float*)d_in[6];
  float* out = (float*)d_out;
  const int E = in_sizes[0] / 2;

  // 512 resident blocks (2/CU x 256 CU); grid = 2 balanced passes
  dim3 grid(1024), block(512);
  hipLaunchKernelGGL(edge_mlp, grid, block, 0, stream,
                     eidx, nf, ef, W1, b1, W2, b2, out, E);
}